// Round 13
// baseline (28.434 us; speedup 1.0000x reference)
//
#include <hip/hip_runtime.h>

// B=8, N=128, COOR=3, F=128, FILT=128
#define BB   8
#define NN   128
#define FF   128
#define KK   128

typedef float f32x4 __attribute__((ext_vector_type(4)));

// ---------------------------------------------------------------------------
// Kernel 1: AC[bn][c][256]: cols 0..127 = A+bias/2, 128..255 = C+bias/2.
//   A[bn,c,k] = sum_f vf[bn,c,f] * w[f,k];  C[bn,c,k] uses w[128+f,k].
// R12 lesson: prior k_pre variants were VMEM-ISSUE bound (7 VMEM instrs per
// 6 FMAs ~= 12us regardless of wave count). This version: thread = (kq =
// f32x4 of the 256-col concat space, fh = f-half, r = row). Per 4-f group:
// 4x b128 w loads (VMEM) + 3x b128 vf broadcasts (LDS pipe) + 48 FMAs ->
// ~0.9us VMEM, ~1.3us VALU, ~1-2us LDS per CU. Grid 512 x 256 (8 waves/CU).
// Cross-fh reduce via 6KB LDS.
// ---------------------------------------------------------------------------
__global__ __launch_bounds__(256) void k_pre(const float* __restrict__ vf,
                                             const float* __restrict__ w,
                                             const float* __restrict__ bias,
                                             float* __restrict__ ac) {
    const int bn0 = blockIdx.x * 2;
    const int tid = threadIdx.x;
    __shared__ __align__(16) float vfr[768];   // 2 rows x 3 coor x 128
    __shared__ f32x4 red[128][3];              // fh=1 partials, slot=(r,kq)

    if (tid < 192) {
        ((f32x4*)vfr)[tid] = ((const f32x4*)(vf + (size_t)bn0 * 384))[tid];
    }
    __syncthreads();

    const int kq = tid & 63;            // f32x4 index in 256-col concat space
    const int fh = (tid >> 6) & 1;      // f-half
    const int r  = tid >> 7;            // row within block
    // w row: A-half (kq<32) rows [0..128), C-half rows [128..256); +fh*64+f.
    const int wrow0 = (kq < 32 ? 0 : 128) + fh * 64;
    const int wcol  = (kq & 31) * 4;
    const float* wp = w + (size_t)wrow0 * KK + wcol;
    const float* vp = vfr + r * 384 + fh * 64;

    f32x4 acc0 = {0.f,0.f,0.f,0.f}, acc1 = acc0, acc2 = acc0;
#pragma unroll 2
    for (int g = 0; g < 16; ++g) {      // 16 groups x 4 f
        const int f = g * 4;
        const f32x4 w0 = *(const f32x4*)(wp + (size_t)(f + 0) * KK);
        const f32x4 w1 = *(const f32x4*)(wp + (size_t)(f + 1) * KK);
        const f32x4 w2 = *(const f32x4*)(wp + (size_t)(f + 2) * KK);
        const f32x4 w3 = *(const f32x4*)(wp + (size_t)(f + 3) * KK);
        const f32x4 v0 = *(const f32x4*)(vp + f);         // c=0, f..f+3
        const f32x4 v1 = *(const f32x4*)(vp + 128 + f);   // c=1
        const f32x4 v2 = *(const f32x4*)(vp + 256 + f);   // c=2
        acc0 += w0 * v0.x + w1 * v0.y + w2 * v0.z + w3 * v0.w;
        acc1 += w0 * v1.x + w1 * v1.y + w2 * v1.z + w3 * v1.w;
        acc2 += w0 * v2.x + w1 * v2.y + w2 * v2.z + w3 * v2.w;
    }

    const int slot = r * 64 + kq;
    if (fh) {
        red[slot][0] = acc0; red[slot][1] = acc1; red[slot][2] = acc2;
    }
    __syncthreads();
    if (!fh) {
        const f32x4 hb = 0.5f * *(const f32x4*)(bias + (kq & 31) * 4);
        f32x4* dst = (f32x4*)(ac + (size_t)(bn0 + r) * 768) + kq;  // c-stride 64
        dst[0]   = acc0 + red[slot][0] + hb;
        dst[64]  = acc1 + red[slot][1] + hb;
        dst[128] = acc2 + red[slot][2] + hb;
    }
}

// ---------------------------------------------------------------------------
// Kernel 2: out[b,i,j,k] = sum_c d[b,i,j,c] * (A'[b,i,c,k] + C'[b,j,c,k])
// R10 version byte-identical (best known: ~write-floor. grid 2048, dist-LDS,
// wave-uniform i -> contiguous 1KB wave stores, full unroll, NT stores).
// ---------------------------------------------------------------------------
__global__ __launch_bounds__(256) void k_main(const float* __restrict__ dist,
                                              const float* __restrict__ ac,
                                              float* __restrict__ out) {
    const int bx  = blockIdx.x;
    const int b   = bx >> 8;            // 256 blocks per batch
    const int rem = bx & 255;
    const int it  = rem >> 3;           // 0..31
    const int jt  = rem & 7;            // 0..7 (low bits -> XCD affinity on C)
    const int i0  = it * 4, j0 = jt * 16;
    const int tid = threadIdx.x;

    __shared__ float dl[192];           // [ti][jj][c] = 4 x 16 x 3
    if (tid < 192) {
        const int ti = tid / 48, r = tid % 48;
        dl[tid] = dist[((size_t)(b * NN + i0 + ti) * NN + j0) * 3 + r];
    }
    __syncthreads();

    const int k4 = tid & 31;
    const int rg = tid >> 5;            // 0..7
    const int ti = rg >> 1;             // 0..3, constant per WAVE
    const int jp = rg & 1;              // j parity within wave
    const int i  = i0 + ti;

    const float4* arow = (const float4*)(ac + (size_t)(b * NN + i) * 768) + k4;
    const float4 a0 = arow[0], a1 = arow[64], a2 = arow[128];
    float* obase = out + (size_t)(b * NN + i) * NN * KK;
    const float* dlt = dl + ti * 48;

#pragma unroll
    for (int p = 0; p < 8; ++p) {
        const int jj = 2 * p + jp;
        const int j  = j0 + jj;
        const float d0 = dlt[jj * 3], d1 = dlt[jj * 3 + 1], d2 = dlt[jj * 3 + 2];

        const float4* crow = (const float4*)(ac + (size_t)(b * NN + j) * 768)
                             + 32 + k4;          // +128 floats: C-half
        const float4 c0 = crow[0], c1 = crow[64], c2 = crow[128];

        f32x4 r;
        r.x = fmaf(d0, a0.x + c0.x, fmaf(d1, a1.x + c1.x, d2 * (a2.x + c2.x)));
        r.y = fmaf(d0, a0.y + c0.y, fmaf(d1, a1.y + c1.y, d2 * (a2.y + c2.y)));
        r.z = fmaf(d0, a0.z + c0.z, fmaf(d1, a1.z + c1.z, d2 * (a2.z + c2.z)));
        r.w = fmaf(d0, a0.w + c0.w, fmaf(d1, a1.w + c1.w, d2 * (a2.w + c2.w)));

        __builtin_nontemporal_store(r, (f32x4*)(obase + (size_t)j * KK + k4 * 4));
    }
}

// ---------------------------------------------------------------------------
// Fallback (only if ws_size < 3 MB): fused, recomputes C per j. Slow but correct.
// ---------------------------------------------------------------------------
__global__ __launch_bounds__(256) void k_fused_slow(const float* __restrict__ vf,
                                                    const float* __restrict__ dist,
                                                    const float* __restrict__ w,
                                                    const float* __restrict__ bias,
                                                    float* __restrict__ out) {
    const int bi  = blockIdx.x;           // b*NN + i
    const int b   = bi >> 7;
    const int tid = threadIdx.x;
    __shared__ float arow[384];
    __shared__ float crow[384];

    for (int idx = tid; idx < 384; idx += 256) {
        const int c = idx >> 7, k = idx & 127;
        const float* v = vf + (size_t)bi * 384 + c * 128;
        float s = 0.f;
        for (int f = 0; f < 128; ++f) s = fmaf(v[f], w[f * 128 + k], s);
        arow[idx] = s;
    }
    __syncthreads();

    for (int j = 0; j < NN; ++j) {
        for (int idx = tid; idx < 384; idx += 256) {
            const int c = idx >> 7, k = idx & 127;
            const float* v = vf + (size_t)(b * NN + j) * 384 + c * 128;
            float s = 0.f;
            for (int f = 0; f < 128; ++f) s = fmaf(v[f], w[(128 + f) * 128 + k], s);
            crow[idx] = s;
        }
        __syncthreads();
        if (tid < 128) {
            const float* dj = dist + ((size_t)bi * NN + j) * 3;
            const float d0 = dj[0], d1 = dj[1], d2 = dj[2];
            const float sd = d0 + d1 + d2;
            const float r = fmaf(d0, arow[tid] + crow[tid],
                            fmaf(d1, arow[128 + tid] + crow[128 + tid],
                            fmaf(d2, arow[256 + tid] + crow[256 + tid], sd * bias[tid])));
            out[((size_t)bi * NN + j) * 128 + tid] = r;
        }
        __syncthreads();
    }
}

extern "C" void kernel_launch(void* const* d_in, const int* in_sizes, int n_in,
                              void* d_out, int out_size, void* d_ws, size_t ws_size,
                              hipStream_t stream) {
    const float* vf   = (const float*)d_in[0];   // [8,128,3,128]
    const float* dist = (const float*)d_in[1];   // [8,128,128,3]
    const float* w    = (const float*)d_in[2];   // [256,128]
    const float* bias = (const float*)d_in[3];   // [128]
    float* out = (float*)d_out;                  // [8,128,128,128]

    const size_t need = (size_t)BB * NN * 3 * 256 * sizeof(float);  // 3 MB
    if (ws_size >= need) {
        float* ac = (float*)d_ws;
        k_pre<<<512, 256, 0, stream>>>(vf, w, bias, ac);
        k_main<<<2048, 256, 0, stream>>>(dist, ac, out);
    } else {
        k_fused_slow<<<BB * NN, 256, 0, stream>>>(vf, dist, w, bias, out);
    }
}

// Round 14
// 25.208 us; speedup vs baseline: 1.1280x; 1.1280x over previous
//
#include <hip/hip_runtime.h>

// B=8, N=128, COOR=3, F=128, FILT=128
#define BB   8
#define NN   128
#define FF   128
#define KK   128

typedef float  f32x4  __attribute__((ext_vector_type(4)));
typedef short  bf16x8 __attribute__((ext_vector_type(8)));
typedef short  short4v __attribute__((ext_vector_type(4)));

__device__ __forceinline__ short f2bf(float x) {
    union { float f; unsigned u; } v; v.f = x;
    unsigned u = v.u + (0x7fffu + ((v.u >> 16) & 1u));   // RTNE
    return (short)(u >> 16);
}

// ---------------------------------------------------------------------------
// Kernel 1 (MFMA): AC[M=3072][256] = bf16(vf)[3072][128] @ bf16(wcat)[128][256]
//   + 0.5*bias[n&127].  M-row = bn*3+c (vf's natural flat order); concat col
//   n<128 -> w rows 0..127 (A-half), n>=128 -> w rows 128..255 (C-half).
// Block = 1 M-tile (16 rows) x 4 N-tiles (1/wave). Grid 768 x 256.
// LDS: A-tile 16x(128+8pad) bf16, B-tile 64x(128+8pad) bf16 (col-major by n).
// Row pad +8 shorts -> frag ds_read_b128 is 2-way bank aliased (free, m136).
// A and B frags use the SAME linear k packing (k = s*32 + (lane>>4)*8 + j),
// so any internal k->slot permutation cancels in the contraction.
// C/D: col = lane&15, row = (lane>>4)*4 + reg  [m89-verified].
// ---------------------------------------------------------------------------
#define LROW 136   // 128 + 8 pad (shorts)

__global__ __launch_bounds__(256) void k_pre_mfma(const float* __restrict__ vf,
                                                  const float* __restrict__ w,
                                                  const float* __restrict__ bias,
                                                  float* __restrict__ ac) {
    const int bx  = blockIdx.x;
    const int mt  = bx >> 2;            // 0..191  M-tile
    const int ntq = bx & 3;             // 0..3    N-quad (low bits -> XCD spread)
    const int tid = threadIdx.x;

    __shared__ short a_lds[16 * LROW];          // 4.25 KB
    __shared__ short b_lds[64 * LROW];          // 17.4 KB

    // ---- Stage A: vf rows mt*16..+16 (fp32) -> bf16 a_lds[m][k] ----
    {
        const f32x4* vfp = (const f32x4*)vf + (size_t)mt * 512;  // 16*128/4
        const int m  = tid >> 4;
        const int k0 = (tid & 15) * 8;
#pragma unroll
        for (int q = 0; q < 2; ++q) {
            const f32x4 v = vfp[tid * 2 + q];
            short4v s;
            s.x = f2bf(v.x); s.y = f2bf(v.y); s.z = f2bf(v.z); s.w = f2bf(v.w);
            *(short4v*)(&a_lds[m * LROW + k0 + q * 4]) = s;
        }
    }
    // ---- Stage B: w[whalf*128 + k][wcol0 + nl] -> bf16 b_lds[nl][k] ----
    {
        const int whalf = ntq >> 1;
        const int wcol0 = (ntq & 1) * 64;
        const int kloc  = tid >> 4;         // 0..15
        const int cq    = tid & 15;         // col quad 0..15 -> nl = cq*4..+4
#pragma unroll
        for (int kb = 0; kb < 8; ++kb) {
            const int k = kb * 16 + kloc;
            const f32x4 v = *(const f32x4*)(w + (size_t)(whalf * 128 + k) * KK
                                              + wcol0 + cq * 4);
            b_lds[(cq * 4 + 0) * LROW + k] = f2bf(v.x);
            b_lds[(cq * 4 + 1) * LROW + k] = f2bf(v.y);
            b_lds[(cq * 4 + 2) * LROW + k] = f2bf(v.z);
            b_lds[(cq * 4 + 3) * LROW + k] = f2bf(v.w);
        }
    }
    __syncthreads();

    // ---- MFMA: one 16x16 tile per wave ----
    const int wid  = tid >> 6;          // 0..3
    const int lane = tid & 63;
    const int lg   = lane >> 4;         // k-group
    const int ln   = lane & 15;         // m for A, n for B, col for D
    const int nt   = ntq * 4 + wid;     // global N-tile 0..15

    f32x4 acc = {0.f, 0.f, 0.f, 0.f};
#pragma unroll
    for (int s = 0; s < 4; ++s) {
        const int k0 = s * 32 + lg * 8;
        const bf16x8 af = *(const bf16x8*)(&a_lds[ln * LROW + k0]);
        const bf16x8 bf = *(const bf16x8*)(&b_lds[(wid * 16 + ln) * LROW + k0]);
        acc = __builtin_amdgcn_mfma_f32_16x16x32_bf16(af, bf, acc, 0, 0, 0);
    }

    // ---- Epilogue: D + 0.5*bias -> ac ----
    const int ncol = nt * 16 + ln;
    const float hb = 0.5f * bias[ncol & 127];
#pragma unroll
    for (int r = 0; r < 4; ++r) {
        const int mrow = mt * 16 + lg * 4 + r;
        ac[(size_t)mrow * 256 + ncol] = acc[r] + hb;
    }
}

// ---------------------------------------------------------------------------
// Kernel 2: out[b,i,j,k] = sum_c d[b,i,j,c] * (A'[b,i,c,k] + C'[b,j,c,k])
// R10 version byte-identical (best known, ~write floor: grid 2048, dist-LDS,
// wave-uniform i -> contiguous 1KB wave NT stores, full unroll).
// ---------------------------------------------------------------------------
__global__ __launch_bounds__(256) void k_main(const float* __restrict__ dist,
                                              const float* __restrict__ ac,
                                              float* __restrict__ out) {
    const int bx  = blockIdx.x;
    const int b   = bx >> 8;            // 256 blocks per batch
    const int rem = bx & 255;
    const int it  = rem >> 3;           // 0..31
    const int jt  = rem & 7;            // 0..7 (low bits -> XCD affinity on C)
    const int i0  = it * 4, j0 = jt * 16;
    const int tid = threadIdx.x;

    __shared__ float dl[192];           // [ti][jj][c] = 4 x 16 x 3
    if (tid < 192) {
        const int ti = tid / 48, r = tid % 48;
        dl[tid] = dist[((size_t)(b * NN + i0 + ti) * NN + j0) * 3 + r];
    }
    __syncthreads();

    const int k4 = tid & 31;
    const int rg = tid >> 5;            // 0..7
    const int ti = rg >> 1;             // 0..3, constant per WAVE
    const int jp = rg & 1;              // j parity within wave
    const int i  = i0 + ti;

    const float4* arow = (const float4*)(ac + (size_t)(b * NN + i) * 768) + k4;
    const float4 a0 = arow[0], a1 = arow[64], a2 = arow[128];
    float* obase = out + (size_t)(b * NN + i) * NN * KK;
    const float* dlt = dl + ti * 48;

#pragma unroll
    for (int p = 0; p < 8; ++p) {
        const int jj = 2 * p + jp;
        const int j  = j0 + jj;
        const float d0 = dlt[jj * 3], d1 = dlt[jj * 3 + 1], d2 = dlt[jj * 3 + 2];

        const float4* crow = (const float4*)(ac + (size_t)(b * NN + j) * 768)
                             + 32 + k4;          // +128 floats: C-half
        const float4 c0 = crow[0], c1 = crow[64], c2 = crow[128];

        f32x4 r;
        r.x = fmaf(d0, a0.x + c0.x, fmaf(d1, a1.x + c1.x, d2 * (a2.x + c2.x)));
        r.y = fmaf(d0, a0.y + c0.y, fmaf(d1, a1.y + c1.y, d2 * (a2.y + c2.y)));
        r.z = fmaf(d0, a0.z + c0.z, fmaf(d1, a1.z + c1.z, d2 * (a2.z + c2.z)));
        r.w = fmaf(d0, a0.w + c0.w, fmaf(d1, a1.w + c1.w, d2 * (a2.w + c2.w)));

        __builtin_nontemporal_store(r, (f32x4*)(obase + (size_t)j * KK + k4 * 4));
    }
}

// ---------------------------------------------------------------------------
// Fallback (only if ws_size < 3 MB): fused, recomputes C per j. Slow but correct.
// ---------------------------------------------------------------------------
__global__ __launch_bounds__(256) void k_fused_slow(const float* __restrict__ vf,
                                                    const float* __restrict__ dist,
                                                    const float* __restrict__ w,
                                                    const float* __restrict__ bias,
                                                    float* __restrict__ out) {
    const int bi  = blockIdx.x;           // b*NN + i
    const int b   = bi >> 7;
    const int tid = threadIdx.x;
    __shared__ float arow[384];
    __shared__ float crow[384];

    for (int idx = tid; idx < 384; idx += 256) {
        const int c = idx >> 7, k = idx & 127;
        const float* v = vf + (size_t)bi * 384 + c * 128;
        float s = 0.f;
        for (int f = 0; f < 128; ++f) s = fmaf(v[f], w[f * 128 + k], s);
        arow[idx] = s;
    }
    __syncthreads();

    for (int j = 0; j < NN; ++j) {
        for (int idx = tid; idx < 384; idx += 256) {
            const int c = idx >> 7, k = idx & 127;
            const float* v = vf + (size_t)(b * NN + j) * 384 + c * 128;
            float s = 0.f;
            for (int f = 0; f < 128; ++f) s = fmaf(v[f], w[(128 + f) * 128 + k], s);
            crow[idx] = s;
        }
        __syncthreads();
        if (tid < 128) {
            const float* dj = dist + ((size_t)bi * NN + j) * 3;
            const float d0 = dj[0], d1 = dj[1], d2 = dj[2];
            const float sd = d0 + d1 + d2;
            const float r = fmaf(d0, arow[tid] + crow[tid],
                            fmaf(d1, arow[128 + tid] + crow[128 + tid],
                            fmaf(d2, arow[256 + tid] + crow[256 + tid], sd * bias[tid])));
            out[((size_t)bi * NN + j) * 128 + tid] = r;
        }
        __syncthreads();
    }
}

extern "C" void kernel_launch(void* const* d_in, const int* in_sizes, int n_in,
                              void* d_out, int out_size, void* d_ws, size_t ws_size,
                              hipStream_t stream) {
    const float* vf   = (const float*)d_in[0];   // [8,128,3,128]
    const float* dist = (const float*)d_in[1];   // [8,128,128,3]
    const float* w    = (const float*)d_in[2];   // [256,128]
    const float* bias = (const float*)d_in[3];   // [128]
    float* out = (float*)d_out;                  // [8,128,128,128]

    const size_t need = (size_t)BB * NN * 3 * 256 * sizeof(float);  // 3 MB
    if (ws_size >= need) {
        float* ac = (float*)d_ws;
        k_pre_mfma<<<768, 256, 0, stream>>>(vf, w, bias, ac);
        k_main<<<2048, 256, 0, stream>>>(dist, ac, out);
    } else {
        k_fused_slow<<<BB * NN, 256, 0, stream>>>(vf, dist, w, bias, out);
    }
}